// Round 6
// baseline (2289.102 us; speedup 1.0000x reference)
//
#include <hip/hip_runtime.h>

#define HID 256
#define HH  64
#define WW  64

typedef _Float16 f16x8 __attribute__((ext_vector_type(8)));
typedef float    f32x4 __attribute__((ext_vector_type(4)));

// LDS-only barrier: wait ds ops, leave global stores in flight.
// sched_barrier(0) fences per skill rule #18.
#define LDS_BARRIER() do {                                   \
    asm volatile("s_waitcnt lgkmcnt(0)" ::: "memory");       \
    __builtin_amdgcn_sched_barrier(0);                       \
    __builtin_amdgcn_s_barrier();                            \
    __builtin_amdgcn_sched_barrier(0);                       \
  } while (0)

// 16 waves (1024 thr) per WG, one WG per batch element n.
// Each wave owns 16 output channels (one 16x16 N-tile): 8 MFMA/step/wave.
// 4 waves/SIMD so issue-cadence gaps and LDS/MFMA latency of one wave are
// filled by the other three — the serial chain is issue-bound at 1 wave/SIMD.
__global__ __launch_bounds__(1024, 4)
void mrf_scan_kernel(const float* __restrict__ x,
                     const float* __restrict__ w_xh,
                     const float* __restrict__ b_xh,
                     const float* __restrict__ w_hh,
                     const float* __restrict__ b_hh,
                     float* __restrict__ out)
{
    const int n   = blockIdx.x;
    const int tid = threadIdx.x;
    const int wv  = tid >> 6;     // wave 0..15
    const int l   = tid & 63;
    const int l15 = l & 15;
    const int lq  = l >> 4;
    const int oc  = wv * 16 + l15;   // this lane's output channel (4x redundant over lq)

    __shared__ __align__(16) _Float16 hbel[WW][HID];   // h of row below, per column
    __shared__ __align__(16) _Float16 hsum[2][HID];    // h_prev + h_below[w_next], ping-pong
    __shared__ __align__(16) float4   xs4[WW];         // per-row x neighbor sums

    // ---- zero-init LDS ----
    {
        unsigned int* z = (unsigned int*)(&hbel[0][0]);
        #pragma unroll
        for (int q = 0; q < (WW*HID/2)/1024; ++q) z[tid + 1024*q] = 0u;
        if (tid < 256) ((unsigned int*)(&hsum[0][0]))[tid] = 0u;
    }

    // ---- preload this wave's N-tile of w_hh as B-fragments ----
    f16x8 Bf[8];
    {
        const float* wr = w_hh + (size_t)oc * HID;
        #pragma unroll
        for (int kf = 0; kf < 8; ++kf) {
            const int g0 = kf*32 + lq*8;
            f16x8 b;
            #pragma unroll
            for (int j = 0; j < 8; ++j) b[j] = (_Float16)wr[g0 + j];
            Bf[kf] = b;
        }
    }

    // per-channel epilogue constants (used by lq==0 lanes)
    const float wx0 = w_xh[oc*3+0];
    const float wx1 = w_xh[oc*3+1];
    const float wx2 = w_xh[oc*3+2];
    const float bx  = b_xh[oc];
    const float bh  = b_hh[oc];

    const int    XP = HH*WW;
    const float* xn = x + (size_t)n * 3 * XP;
    float* outc = out + (size_t)n * HID * XP + (size_t)oc * XP;

    __syncthreads();

    int cur = 0;
    // deferred-write state (meaningful on lq==0 lanes; persists across rows)
    bool     pend = false;
    float    s_pend = 0.f;
    _Float16 h16_pend = (_Float16)0.f;
    float*   optr_pend = outc;
    _Float16* hbptr_pend = &hbel[0][0];

    for (int k = 0; k < HH; ++k) {
        const int i    = HH - 1 - k;
        const int flip = ((i & 1) == 0);   // even rows scan right->left

        // ---- stage x neighbor sums for this row (waves 0..2; c = wave) ----
        if (tid < 192) {
            const int c = tid >> 6, w = tid & 63;
            const float* xc = xn + (size_t)c * XP;
            float s = 0.f;
            if (w > 0)    s += xc[i*WW + w - 1];
            if (w < WW-1) s += xc[i*WW + w + 1];
            if (i > 0)    s += xc[(i-1)*WW + w];
            if (i < HH-1) s += xc[(i+1)*WW + w];
            ((float*)&xs4[w])[c] = s;
            if (c == 0) {
                const float cnt = (float)((w>0) + (w<WW-1) + (i>0) + (i<HH-1));
                ((float*)&xs4[w])[3] = cnt;
            }
        }
        LDS_BARRIER();

        const float Fr = ((i != 0) ? 1.f : 0.f) + ((k != 0) ? 1.f : 0.f);
        float* orow = outc + (size_t)i * WW;

        for (int t = 0; t < WW; ++t) {
            const int w  = flip ? (WW-1-t) : t;
            const int wn = (t < WW-1) ? (flip ? (WW-2-t) : (t+1)) : w;

            // ---- flush deferred writes from the previous step (off-chain:
            // hbel[w_prev] isn't read for >=2 steps; out store is fire-and-forget)
            if (pend && lq == 0) {
                *hbptr_pend = h16_pend;
                *optr_pend  = s_pend;
            }

            // ---- chain reads: A-fragments from hsum[cur] ----
            f16x8 Af[8];
            #pragma unroll
            for (int kf = 0; kf < 8; ++kf)
                Af[kf] = *(const f16x8*)((const char*)(&hsum[cur][0]) + kf*64 + lq*16);

            _Float16 hb = (_Float16)0.f;
            if (lq == 0) hb = hbel[wn][oc];   // next column's below-h (for hsum write)

            // ---- 2 independent 4-deep MFMA chains (8 MFMA total) ----
            f32x4 cA = (f32x4){0.f,0.f,0.f,0.f};
            f32x4 cB = (f32x4){0.f,0.f,0.f,0.f};
            #pragma unroll
            for (int kf = 0; kf < 4; ++kf) {
                cA = __builtin_amdgcn_mfma_f32_16x16x32_f16(Af[kf],   Bf[kf],   cA, 0, 0, 0);
                cB = __builtin_amdgcn_mfma_f32_16x16x32_f16(Af[kf+4], Bf[kf+4], cB, 0, 0, 0);
            }

            // ---- epilogue on lq==0 lanes only (D rows all equal; reg0 valid) ----
            float s = 0.f; _Float16 h16 = (_Float16)0.f;
            if (lq == 0) {
                const float4 xv = xs4[w];
                const float Ft = Fr + ((t != 0 && t != WW-1) ? 1.f : 0.f)
                                    + ((t != 0) ? 1.f : 0.f);
                float pre = xv.w * bx;
                pre = fmaf(xv.x, wx0, pre);
                pre = fmaf(xv.y, wx1, pre);
                pre = fmaf(xv.z, wx2, pre);
                pre = fmaf(Ft,   bh,  pre);

                const float val = cA[0] + cB[0] + pre;
                const float e   = __expf(-val);
                s   = __builtin_amdgcn_rcpf(1.f + e);
                h16 = (_Float16)s;
                // the ONLY on-chain write: next step's A input
                hsum[cur ^ 1][oc] = (t < WW-1) ? (_Float16)(h16 + hb) : h16;
            }

            LDS_BARRIER();

            // set deferred writes for next step
            pend = true;
            s_pend = s; h16_pend = h16;
            hbptr_pend = &hbel[w][oc];
            optr_pend  = orow + w;
            cur ^= 1;
        }
    }

    // flush the final pixel
    if (lq == 0) *optr_pend = s_pend;
}

extern "C" void kernel_launch(void* const* d_in, const int* in_sizes, int n_in,
                              void* d_out, int out_size, void* d_ws, size_t ws_size,
                              hipStream_t stream) {
    const float* x    = (const float*)d_in[0];
    const float* w_xh = (const float*)d_in[1];
    const float* b_xh = (const float*)d_in[2];
    const float* w_hh = (const float*)d_in[3];
    const float* b_hh = (const float*)d_in[4];
    float* out = (float*)d_out;
    (void)in_sizes; (void)n_in; (void)d_ws; (void)ws_size; (void)out_size;

    mrf_scan_kernel<<<dim3(32), dim3(1024), 0, stream>>>(x, w_xh, b_xh, w_hh, b_hh, out);
}